// Round 1
// baseline (1858.962 us; speedup 1.0000x reference)
//
#include <hip/hip_runtime.h>
#include <hip/hip_bf16.h>
#include <math.h>

// GAT pooled-output restructuring:
//  out[g] = ((pooled_gat[g] + cnt_n[g]*gat_bias + sum_eattr[g]@edge_w + cnt_e[g]*edge_b) @ w1 + b1) @ w2 + b2
//  pooled_gat[g] = sum_j P[g][j][head] * h[j]   (P = per-(graph,src,head) sum of alphas, incl. self loops)

#define NG 64   // NUM_GRAPHS

__device__ __forceinline__ float lrelu(float v){ return v > 0.f ? v : 0.2f*v; }

// order-preserving float<->uint for atomicMax on floats
__device__ __forceinline__ unsigned fkey(float f){
  unsigned b = __float_as_uint(f);
  return (b & 0x80000000u) ? ~b : (b | 0x80000000u);
}
__device__ __forceinline__ float funkey(unsigned u){
  unsigned b = (u & 0x80000000u) ? (u & 0x7fffffffu) : ~u;
  return __uint_as_float(b);
}

// ---------------- h = x @ lin_w  (fp32, 32 rows x 128 cols per block, 4x4/thread)
__global__ __launch_bounds__(256) void k_gemm_h(
    const float* __restrict__ x, const float* __restrict__ W,
    float* __restrict__ h, int N)
{
  __shared__ float ldsX[32*128];
  int rb = blockIdx.x * 32;
  for (int idx = threadIdx.x; idx < 32*128/4; idx += 256){
    int r = idx >> 5;            // (idx*4)>>7
    int k = (idx*4) & 127;
    int row = rb + r;
    float4 v = make_float4(0.f,0.f,0.f,0.f);
    if (row < N) v = *(const float4*)&x[(size_t)row*128 + k];
    *(float4*)&ldsX[idx*4] = v;
  }
  __syncthreads();
  int ty = threadIdx.x >> 5, tx = threadIdx.x & 31;
  int r0 = ty*4, c0 = tx*4;
  float acc[4][4] = {};
  #pragma unroll 4
  for (int k = 0; k < 128; ++k){
    float4 b = *(const float4*)&W[k*128 + c0];   // L2-resident (64 KB)
    float a0 = ldsX[(r0+0)*128 + k];
    float a1 = ldsX[(r0+1)*128 + k];
    float a2 = ldsX[(r0+2)*128 + k];
    float a3 = ldsX[(r0+3)*128 + k];
    acc[0][0] += a0*b.x; acc[0][1] += a0*b.y; acc[0][2] += a0*b.z; acc[0][3] += a0*b.w;
    acc[1][0] += a1*b.x; acc[1][1] += a1*b.y; acc[1][2] += a1*b.z; acc[1][3] += a1*b.w;
    acc[2][0] += a2*b.x; acc[2][1] += a2*b.y; acc[2][2] += a2*b.z; acc[2][3] += a2*b.w;
    acc[3][0] += a3*b.x; acc[3][1] += a3*b.y; acc[3][2] += a3*b.z; acc[3][3] += a3*b.w;
  }
  #pragma unroll
  for (int i=0;i<4;++i){
    int row = rb + r0 + i;
    if (row < N){
      float4 v = make_float4(acc[i][0],acc[i][1],acc[i][2],acc[i][3]);
      *(float4*)&h[(size_t)row*128 + c0] = v;
    }
  }
}

// ---------------- per-node: a_src, a_dst, emax init with self-loop logit
__global__ __launch_bounds__(128) void k_node_attn(
    const float* __restrict__ h, const float* __restrict__ att_src,
    const float* __restrict__ att_dst, float* __restrict__ aS,
    float* __restrict__ aD, unsigned* __restrict__ emax_u, int N)
{
  int i = blockIdx.x; if (i >= N) return;
  int t = threadIdx.x;
  float hv = h[(size_t)i*128 + t];
  float ps = hv * att_src[t];     // att flat [head*64+c] == t
  float pd = hv * att_dst[t];
  #pragma unroll
  for (int o=32;o;o>>=1){ ps += __shfl_down(ps,o); pd += __shfl_down(pd,o); }
  if ((t & 63) == 0){
    int head = t >> 6;
    aS[i*2+head] = ps;
    aD[i*2+head] = pd;
    emax_u[i*2+head] = fkey(lrelu(ps+pd));   // self-loop seeds the max
  }
}

// ---------------- edge pass A: segment max (atomicMax on encoded float)
__global__ __launch_bounds__(256) void k_edge_max(
  const int* __restrict__ src, const int* __restrict__ dst,
  const float* __restrict__ aS, const float* __restrict__ aD,
  unsigned* __restrict__ emax_u, int E)
{
  int e = blockIdx.x*256 + threadIdx.x; if (e >= E) return;
  int s = src[e], d = dst[e];
  float2 as = *(const float2*)&aS[(size_t)s*2];
  float2 ad = *(const float2*)&aD[(size_t)d*2];
  atomicMax(&emax_u[d*2+0], fkey(lrelu(as.x+ad.x)));
  atomicMax(&emax_u[d*2+1], fkey(lrelu(as.y+ad.y)));
}

// ---------------- per-node: denom init (self loop) + node count histogram
__global__ __launch_bounds__(256) void k_node_denom(
  const float* __restrict__ aS, const float* __restrict__ aD,
  const unsigned* __restrict__ emax_u, float* __restrict__ denom,
  const int* __restrict__ batch, float* __restrict__ cnt_n, int N)
{
  __shared__ float hc[NG];
  int t = threadIdx.x;
  if (t < NG) hc[t] = 0.f;
  __syncthreads();
  int i = blockIdx.x*256 + t;
  if (i < N){
    float2 as = *(const float2*)&aS[(size_t)i*2];
    float2 ad = *(const float2*)&aD[(size_t)i*2];
    float m0 = funkey(emax_u[i*2+0]);
    float m1 = funkey(emax_u[i*2+1]);
    denom[i*2+0] = __expf(lrelu(as.x+ad.x) - m0);
    denom[i*2+1] = __expf(lrelu(as.y+ad.y) - m1);
    atomicAdd(&hc[batch[i]], 1.f);
  }
  __syncthreads();
  if (t < NG) atomicAdd(&cnt_n[t], hc[t]);
}

// ---------------- edge pass B: softmax denominator
__global__ __launch_bounds__(256) void k_edge_denom(
  const int* __restrict__ src, const int* __restrict__ dst,
  const float* __restrict__ aS, const float* __restrict__ aD,
  const unsigned* __restrict__ emax_u, float* __restrict__ denom, int E)
{
  int e = blockIdx.x*256 + threadIdx.x; if (e >= E) return;
  int s = src[e], d = dst[e];
  float2 as = *(const float2*)&aS[(size_t)s*2];
  float2 ad = *(const float2*)&aD[(size_t)d*2];
  atomicAdd(&denom[d*2+0], __expf(lrelu(as.x+ad.x) - funkey(emax_u[d*2+0])));
  atomicAdd(&denom[d*2+1], __expf(lrelu(as.y+ad.y) - funkey(emax_u[d*2+1])));
}

// ---------------- per-node: self-loop alpha into P (P pre-zeroed)
__global__ __launch_bounds__(256) void k_node_self(
  const float* __restrict__ aS, const float* __restrict__ aD,
  const unsigned* __restrict__ emax_u, const float* __restrict__ denom,
  const int* __restrict__ batch, float* __restrict__ P, int N)
{
  int i = blockIdx.x*256 + threadIdx.x; if (i >= N) return;
  int g = batch[i];
  float2 as = *(const float2*)&aS[(size_t)i*2];
  float2 ad = *(const float2*)&aD[(size_t)i*2];
  #pragma unroll
  for (int hh=0; hh<2; ++hh){
    float av = hh ? (as.y+ad.y) : (as.x+ad.x);
    float m = funkey(emax_u[i*2+hh]);
    float den = denom[i*2+hh];
    P[(size_t)g*2*N + (size_t)i*2 + hh] = __expf(lrelu(av) - m) / (den + 1e-16f);
  }
}

// ---------------- edge pass C: alpha scatter into P
__global__ __launch_bounds__(256) void k_edge_alpha(
  const int* __restrict__ src, const int* __restrict__ dst,
  const float* __restrict__ aS, const float* __restrict__ aD,
  const unsigned* __restrict__ emax_u, const float* __restrict__ denom,
  const int* __restrict__ batch, float* __restrict__ P, int N, int E)
{
  int e = blockIdx.x*256 + threadIdx.x; if (e >= E) return;
  int s = src[e], d = dst[e];
  int g = batch[d];
  float2 as = *(const float2*)&aS[(size_t)s*2];
  float2 ad = *(const float2*)&aD[(size_t)d*2];
  float a0 = __expf(lrelu(as.x+ad.x) - funkey(emax_u[d*2+0])) / (denom[d*2+0] + 1e-16f);
  float a1 = __expf(lrelu(as.y+ad.y) - funkey(emax_u[d*2+1])) / (denom[d*2+1] + 1e-16f);
  atomicAdd(&P[(size_t)g*2*N + (size_t)s*2 + 0], a0);
  atomicAdd(&P[(size_t)g*2*N + (size_t)s*2 + 1], a1);
}

// ---------------- pooled_gat[g][c] = sum_j P[g][j][c>>6] * h[j][c]
__global__ __launch_bounds__(128) void k_pgemm(
  const float* __restrict__ P, const float* __restrict__ h,
  float* __restrict__ pooled_gat, int N)
{
  __shared__ float ldsP[NG*128];   // [g][jj*2+head] for 64-node subchunk
  int c = threadIdx.x, head = c >> 6;
  float acc[NG];
  #pragma unroll
  for (int g=0; g<NG; ++g) acc[g] = 0.f;
  int jb = blockIdx.x * 256;
  for (int sub=0; sub<4; ++sub){
    int j0 = jb + sub*64;
    __syncthreads();
    for (int idx=c; idx<NG*128; idx+=128){
      int g = idx >> 7, t = idx & 127;
      int j = j0 + (t >> 1);
      ldsP[idx] = (j < N) ? P[(size_t)g*2*N + (size_t)j*2 + (t&1)] : 0.f;
    }
    __syncthreads();
    for (int jj=0; jj<64; ++jj){
      int j = j0 + jj;
      float hv = (j < N) ? h[(size_t)j*128 + c] : 0.f;
      #pragma unroll
      for (int g=0; g<NG; ++g)
        acc[g] += ldsP[g*128 + jj*2 + head] * hv;   // broadcast LDS read
    }
  }
  #pragma unroll
  for (int g=0; g<NG; ++g)
    atomicAdd(&pooled_gat[g*128 + c], acc[g]);
}

// ---------------- per-graph edge_attr sums (streams the 819 MB)
__global__ __launch_bounds__(256) void k_eattr_pool(
  const float* __restrict__ ea, const int* __restrict__ src,
  const int* __restrict__ batch, float* __restrict__ pooled_e,
  float* __restrict__ cnt_e, long long E)
{
  __shared__ float acc[NG*128];
  __shared__ float scnt[NG];
  int t = threadIdx.x;
  for (int idx=t; idx<NG*128; idx+=256) acc[idx] = 0.f;
  if (t < NG) scnt[t] = 0.f;
  __syncthreads();
  int lane = t & 31, sub = t >> 5;            // 8 edges in flight, 32 lanes * float4
  long long per = (E + (long long)gridDim.x - 1) / (long long)gridDim.x;
  long long e0 = (long long)blockIdx.x * per;
  long long e1 = e0 + per; if (e1 > E) e1 = E;
  for (long long e = e0 + sub; e < e1; e += 8){
    int s = src[e];
    int g = batch[s];
    float4 v = *(const float4*)&ea[e*128 + lane*4];
    float* a = &acc[g*128 + lane*4];
    atomicAdd(a+0, v.x); atomicAdd(a+1, v.y);
    atomicAdd(a+2, v.z); atomicAdd(a+3, v.w);
    if (lane == 0) atomicAdd(&scnt[g], 1.f);
  }
  __syncthreads();
  for (int idx=t; idx<NG*128; idx+=256) atomicAdd(&pooled_e[idx], acc[idx]);
  if (t < NG) atomicAdd(&cnt_e[t], scnt[t]);
}

// ---------------- final: combine + edge_w GEMM + MLP, one block per graph
__global__ __launch_bounds__(128) void k_final(
  const float* __restrict__ pooled_gat, const float* __restrict__ pooled_e,
  const float* __restrict__ cnt_n, const float* __restrict__ cnt_e,
  const float* __restrict__ gat_bias, const float* __restrict__ edge_w,
  const float* __restrict__ edge_b, const float* __restrict__ w1,
  const float* __restrict__ b1, const float* __restrict__ w2,
  const float* __restrict__ b2, float* __restrict__ out)
{
  __shared__ float lds_e[128], comb[128], t1[32];
  int g = blockIdx.x, c = threadIdx.x;
  lds_e[c] = pooled_e[g*128 + c];
  __syncthreads();
  float acc = pooled_gat[g*128 + c] + cnt_n[g]*gat_bias[c] + cnt_e[g]*edge_b[c];
  for (int k=0; k<128; ++k) acc += lds_e[k] * edge_w[k*128 + c];
  comb[c] = acc;
  __syncthreads();
  if (c < 32){
    float tv = b1[c];
    for (int k=0; k<128; ++k) tv += comb[k] * w1[k*32 + c];
    t1[c] = tv;
  }
  __syncthreads();
  if (c == 0){
    float o = b2[0];
    #pragma unroll
    for (int m=0; m<32; ++m) o += t1[m] * w2[m];
    out[g] = o;
  }
}

extern "C" void kernel_launch(void* const* d_in, const int* in_sizes, int n_in,
                              void* d_out, int out_size, void* d_ws, size_t ws_size,
                              hipStream_t stream) {
  const float* x        = (const float*)d_in[0];
  const int*   ei       = (const int*)d_in[1];
  const float* ea       = (const float*)d_in[2];
  const int*   batch    = (const int*)d_in[3];
  const float* lin_w    = (const float*)d_in[4];
  const float* att_src  = (const float*)d_in[5];
  const float* att_dst  = (const float*)d_in[6];
  const float* gat_bias = (const float*)d_in[7];
  const float* edge_w   = (const float*)d_in[8];
  const float* edge_b   = (const float*)d_in[9];
  const float* w1       = (const float*)d_in[10];
  const float* b1       = (const float*)d_in[11];
  const float* w2       = (const float*)d_in[12];
  const float* b2       = (const float*)d_in[13];
  float* out = (float*)d_out;

  int N = in_sizes[0] / 128;
  int E = in_sizes[1] / 2;
  const int* src = ei;
  const int* dst = ei + E;

  char* ws = (char*)d_ws;
  size_t off = 0;
  float* P          = (float*)(ws + off); off += (size_t)NG*2*N*4;   // zeroed
  float* pooled_gat = (float*)(ws + off); off += (size_t)NG*128*4;   // zeroed
  float* pooled_e   = (float*)(ws + off); off += (size_t)NG*128*4;   // zeroed
  float* cnt_n      = (float*)(ws + off); off += NG*4;               // zeroed
  float* cnt_e      = (float*)(ws + off); off += NG*4;               // zeroed
  size_t zero_bytes = off;
  float* h       = (float*)(ws + off); off += (size_t)N*128*4;
  float* aS      = (float*)(ws + off); off += (size_t)2*N*4;
  float* aD      = (float*)(ws + off); off += (size_t)2*N*4;
  unsigned* emax = (unsigned*)(ws + off); off += (size_t)2*N*4;
  float* denom   = (float*)(ws + off); off += (size_t)2*N*4;

  hipMemsetAsync(d_ws, 0, zero_bytes, stream);

  k_gemm_h   <<<(N+31)/32, 256, 0, stream>>>(x, lin_w, h, N);
  k_node_attn<<<N, 128, 0, stream>>>(h, att_src, att_dst, aS, aD, emax, N);
  k_edge_max <<<(E+255)/256, 256, 0, stream>>>(src, dst, aS, aD, emax, E);
  k_node_denom<<<(N+255)/256, 256, 0, stream>>>(aS, aD, emax, denom, batch, cnt_n, N);
  k_edge_denom<<<(E+255)/256, 256, 0, stream>>>(src, dst, aS, aD, emax, denom, E);
  k_node_self<<<(N+255)/256, 256, 0, stream>>>(aS, aD, emax, denom, batch, P, N);
  k_edge_alpha<<<(E+255)/256, 256, 0, stream>>>(src, dst, aS, aD, emax, denom, batch, P, N, E);
  k_pgemm    <<<(N+255)/256, 128, 0, stream>>>(P, h, pooled_gat, N);
  k_eattr_pool<<<512, 256, 0, stream>>>(ea, src, batch, pooled_e, cnt_e, (long long)E);
  k_final    <<<NG, 128, 0, stream>>>(pooled_gat, pooled_e, cnt_n, cnt_e,
                                      gat_bias, edge_w, edge_b, w1, b1, w2, b2, out);
}

// Round 2
// 1279.194 us; speedup vs baseline: 1.4532x; 1.4532x over previous
//
#include <hip/hip_runtime.h>
#include <hip/hip_bf16.h>
#include <math.h>

// GAT pooled-output restructuring:
//  out[g] = ((pooled_gat[g] + cnt_n[g]*gat_bias + sum_eattr[g]@edge_w + cnt_e[g]*edge_b) @ w1 + b1) @ w2 + b2
//  pooled_gat[g] = sum_j P[g][j][head] * h[j]   (P = per-(graph,src,head) sum of alphas, incl. self loops)
// edge_attr branch: counting-sort edges by graph (g = batch[src]), then stream
// 819 MB of edge_attr with pure register accumulation (no atomics in hot loop).

#define NG 64   // NUM_GRAPHS

__device__ __forceinline__ float lrelu(float v){ return v > 0.f ? v : 0.2f*v; }

// order-preserving float<->uint for atomicMax on floats
__device__ __forceinline__ unsigned fkey(float f){
  unsigned b = __float_as_uint(f);
  return (b & 0x80000000u) ? ~b : (b | 0x80000000u);
}
__device__ __forceinline__ float funkey(unsigned u){
  unsigned b = (u & 0x80000000u) ? (u & 0x7fffffffu) : ~u;
  return __uint_as_float(b);
}

// ---------------- h = x @ lin_w  (fp32, 32 rows x 128 cols per block, 4x4/thread)
__global__ __launch_bounds__(256) void k_gemm_h(
    const float* __restrict__ x, const float* __restrict__ W,
    float* __restrict__ h, int N)
{
  __shared__ float ldsX[32*128];
  int rb = blockIdx.x * 32;
  for (int idx = threadIdx.x; idx < 32*128/4; idx += 256){
    int k = (idx*4) & 127;
    int row = rb + (idx >> 5);
    float4 v = make_float4(0.f,0.f,0.f,0.f);
    if (row < N) v = *(const float4*)&x[(size_t)row*128 + k];
    *(float4*)&ldsX[idx*4] = v;
  }
  __syncthreads();
  int ty = threadIdx.x >> 5, tx = threadIdx.x & 31;
  int r0 = ty*4, c0 = tx*4;
  float acc[4][4] = {};
  #pragma unroll 4
  for (int k = 0; k < 128; ++k){
    float4 b = *(const float4*)&W[k*128 + c0];   // L2-resident (64 KB)
    float a0 = ldsX[(r0+0)*128 + k];
    float a1 = ldsX[(r0+1)*128 + k];
    float a2 = ldsX[(r0+2)*128 + k];
    float a3 = ldsX[(r0+3)*128 + k];
    acc[0][0] += a0*b.x; acc[0][1] += a0*b.y; acc[0][2] += a0*b.z; acc[0][3] += a0*b.w;
    acc[1][0] += a1*b.x; acc[1][1] += a1*b.y; acc[1][2] += a1*b.z; acc[1][3] += a1*b.w;
    acc[2][0] += a2*b.x; acc[2][1] += a2*b.y; acc[2][2] += a2*b.z; acc[2][3] += a2*b.w;
    acc[3][0] += a3*b.x; acc[3][1] += a3*b.y; acc[3][2] += a3*b.z; acc[3][3] += a3*b.w;
  }
  #pragma unroll
  for (int i=0;i<4;++i){
    int row = rb + r0 + i;
    if (row < N){
      float4 v = make_float4(acc[i][0],acc[i][1],acc[i][2],acc[i][3]);
      *(float4*)&h[(size_t)row*128 + c0] = v;
    }
  }
}

// ---------------- per-node: a_src, a_dst, emax init with self-loop logit
__global__ __launch_bounds__(128) void k_node_attn(
    const float* __restrict__ h, const float* __restrict__ att_src,
    const float* __restrict__ att_dst, float* __restrict__ aS,
    float* __restrict__ aD, unsigned* __restrict__ emax_u, int N)
{
  int i = blockIdx.x; if (i >= N) return;
  int t = threadIdx.x;
  float hv = h[(size_t)i*128 + t];
  float ps = hv * att_src[t];     // att flat [head*64+c] == t
  float pd = hv * att_dst[t];
  #pragma unroll
  for (int o=32;o;o>>=1){ ps += __shfl_down(ps,o); pd += __shfl_down(pd,o); }
  if ((t & 63) == 0){
    int head = t >> 6;
    aS[i*2+head] = ps;
    aD[i*2+head] = pd;
    emax_u[i*2+head] = fkey(lrelu(ps+pd));   // self-loop seeds the max
  }
}

// ---------------- edge pass A: segment max (atomicMax on encoded float)
__global__ __launch_bounds__(256) void k_edge_max(
  const int* __restrict__ src, const int* __restrict__ dst,
  const float* __restrict__ aS, const float* __restrict__ aD,
  unsigned* __restrict__ emax_u, int E)
{
  int e = blockIdx.x*256 + threadIdx.x; if (e >= E) return;
  int s = src[e], d = dst[e];
  float2 as = *(const float2*)&aS[(size_t)s*2];
  float2 ad = *(const float2*)&aD[(size_t)d*2];
  atomicMax(&emax_u[d*2+0], fkey(lrelu(as.x+ad.x)));
  atomicMax(&emax_u[d*2+1], fkey(lrelu(as.y+ad.y)));
}

// ---------------- per-node: denom init (self loop) + node count histogram
__global__ __launch_bounds__(256) void k_node_denom(
  const float* __restrict__ aS, const float* __restrict__ aD,
  const unsigned* __restrict__ emax_u, float* __restrict__ denom,
  const int* __restrict__ batch, float* __restrict__ cnt_n, int N)
{
  __shared__ float hc[NG];
  int t = threadIdx.x;
  if (t < NG) hc[t] = 0.f;
  __syncthreads();
  int i = blockIdx.x*256 + t;
  if (i < N){
    float2 as = *(const float2*)&aS[(size_t)i*2];
    float2 ad = *(const float2*)&aD[(size_t)i*2];
    float m0 = funkey(emax_u[i*2+0]);
    float m1 = funkey(emax_u[i*2+1]);
    denom[i*2+0] = __expf(lrelu(as.x+ad.x) - m0);
    denom[i*2+1] = __expf(lrelu(as.y+ad.y) - m1);
    atomicAdd(&hc[batch[i]], 1.f);
  }
  __syncthreads();
  if (t < NG) atomicAdd(&cnt_n[t], hc[t]);
}

// ---------------- edge pass B: softmax denominator
__global__ __launch_bounds__(256) void k_edge_denom(
  const int* __restrict__ src, const int* __restrict__ dst,
  const float* __restrict__ aS, const float* __restrict__ aD,
  const unsigned* __restrict__ emax_u, float* __restrict__ denom, int E)
{
  int e = blockIdx.x*256 + threadIdx.x; if (e >= E) return;
  int s = src[e], d = dst[e];
  float2 as = *(const float2*)&aS[(size_t)s*2];
  float2 ad = *(const float2*)&aD[(size_t)d*2];
  atomicAdd(&denom[d*2+0], __expf(lrelu(as.x+ad.x) - funkey(emax_u[d*2+0])));
  atomicAdd(&denom[d*2+1], __expf(lrelu(as.y+ad.y) - funkey(emax_u[d*2+1])));
}

// ---------------- per-node: self-loop alpha into P (P pre-zeroed)
__global__ __launch_bounds__(256) void k_node_self(
  const float* __restrict__ aS, const float* __restrict__ aD,
  const unsigned* __restrict__ emax_u, const float* __restrict__ denom,
  const int* __restrict__ batch, float* __restrict__ P, int N)
{
  int i = blockIdx.x*256 + threadIdx.x; if (i >= N) return;
  int g = batch[i];
  float2 as = *(const float2*)&aS[(size_t)i*2];
  float2 ad = *(const float2*)&aD[(size_t)i*2];
  #pragma unroll
  for (int hh=0; hh<2; ++hh){
    float av = hh ? (as.y+ad.y) : (as.x+ad.x);
    float m = funkey(emax_u[i*2+hh]);
    float den = denom[i*2+hh];
    P[(size_t)g*2*N + (size_t)i*2 + hh] = __expf(lrelu(av) - m) / (den + 1e-16f);
  }
}

// ---------------- edge pass C: alpha scatter into P
__global__ __launch_bounds__(256) void k_edge_alpha(
  const int* __restrict__ src, const int* __restrict__ dst,
  const float* __restrict__ aS, const float* __restrict__ aD,
  const unsigned* __restrict__ emax_u, const float* __restrict__ denom,
  const int* __restrict__ batch, float* __restrict__ P, int N, int E)
{
  int e = blockIdx.x*256 + threadIdx.x; if (e >= E) return;
  int s = src[e], d = dst[e];
  int g = batch[d];
  float2 as = *(const float2*)&aS[(size_t)s*2];
  float2 ad = *(const float2*)&aD[(size_t)d*2];
  float a0 = __expf(lrelu(as.x+ad.x) - funkey(emax_u[d*2+0])) / (denom[d*2+0] + 1e-16f);
  float a1 = __expf(lrelu(as.y+ad.y) - funkey(emax_u[d*2+1])) / (denom[d*2+1] + 1e-16f);
  atomicAdd(&P[(size_t)g*2*N + (size_t)s*2 + 0], a0);
  atomicAdd(&P[(size_t)g*2*N + (size_t)s*2 + 1], a1);
}

// ---------------- pooled_gat[g][c] = sum_j P[g][j][c>>6] * h[j][c]
__global__ __launch_bounds__(128) void k_pgemm(
  const float* __restrict__ P, const float* __restrict__ h,
  float* __restrict__ pooled_gat, int N)
{
  __shared__ float ldsP[NG*128];   // [g][jj*2+head] for 64-node subchunk
  int c = threadIdx.x, head = c >> 6;
  float acc[NG];
  #pragma unroll
  for (int g=0; g<NG; ++g) acc[g] = 0.f;
  int jb = blockIdx.x * 256;
  for (int sub=0; sub<4; ++sub){
    int j0 = jb + sub*64;
    __syncthreads();
    for (int idx=c; idx<NG*128; idx+=128){
      int g = idx >> 7, t = idx & 127;
      int j = j0 + (t >> 1);
      ldsP[idx] = (j < N) ? P[(size_t)g*2*N + (size_t)j*2 + (t&1)] : 0.f;
    }
    __syncthreads();
    for (int jj=0; jj<64; ++jj){
      int j = j0 + jj;
      float hv = (j < N) ? h[(size_t)j*128 + c] : 0.f;
      #pragma unroll
      for (int g=0; g<NG; ++g)
        acc[g] += ldsP[g*128 + jj*2 + head] * hv;   // broadcast LDS read
    }
  }
  #pragma unroll
  for (int g=0; g<NG; ++g)
    atomicAdd(&pooled_gat[g*128 + c], acc[g]);
}

// ================= edge_attr branch: counting sort by graph, then stream ====

// ---- pass A: g_e[e] = batch[src[e]] + per-block histogram -> gcnt
__global__ __launch_bounds__(256) void k_edge_graph(
  const int* __restrict__ src, const int* __restrict__ batch,
  int* __restrict__ g_e, int* __restrict__ gcnt, int E)
{
  __shared__ int hh[NG];
  int t = threadIdx.x;
  if (t < NG) hh[t] = 0;
  __syncthreads();
  int e = blockIdx.x*256 + t;
  if (e < E){
    int g = batch[src[e]];
    g_e[e] = g;
    atomicAdd(&hh[g], 1);
  }
  __syncthreads();
  if (t < NG) atomicAdd(&gcnt[t], hh[t]);
}

// ---- pass B: exclusive prefix sum (tiny, 1 block)
__global__ void k_scan(const int* __restrict__ gcnt, int* __restrict__ goff,
                       int* __restrict__ gpos, float* __restrict__ cnt_e)
{
  if (threadIdx.x == 0){
    int s = 0;
    for (int g = 0; g < NG; ++g){
      goff[g] = s; gpos[g] = s;
      cnt_e[g] = (float)gcnt[g];
      s += gcnt[g];
    }
  }
}

// ---- pass C: block-aggregated stable scatter of edge ids grouped by graph
__global__ __launch_bounds__(256) void k_scatter(
  const int* __restrict__ g_e, int* __restrict__ order,
  int* __restrict__ gpos, int E)
{
  __shared__ int lcnt[NG];
  __shared__ int lbase[NG];
  int t = threadIdx.x;
  if (t < NG) lcnt[t] = 0;
  __syncthreads();
  int e = blockIdx.x*256 + t;
  int g = 0, r = 0;
  if (e < E){
    g = g_e[e];
    r = atomicAdd(&lcnt[g], 1);
  }
  __syncthreads();
  if (t < NG) lbase[t] = atomicAdd(&gpos[t], lcnt[t]);
  __syncthreads();
  if (e < E) order[lbase[g] + r] = e;
}

// ---- pass D: per-graph streaming sum of edge_attr (register accumulation)
// grid = NG * SPLITS blocks; block (g, k) handles slice k of graph g's edges.
#define EA_SPLITS 64
__global__ __launch_bounds__(256) void k_eattr_sum(
  const float* __restrict__ ea, const int* __restrict__ order,
  const int* __restrict__ goff, const int* __restrict__ gcnt,
  float* __restrict__ pooled_e)
{
  __shared__ int sord[512];
  __shared__ float facc[128];
  int g = blockIdx.x / EA_SPLITS, k = blockIdx.x % EA_SPLITS;
  int start = goff[g], cnt = gcnt[g];
  int len = (cnt + EA_SPLITS - 1) / EA_SPLITS;
  int i0 = start + k*len;
  int i1 = start + cnt; if (i0 + len < i1) i1 = i0 + len;
  int t = threadIdx.x, lane = t & 31, sub = t >> 5;  // 8 subgroups x 32 lanes
  float4 acc = make_float4(0.f,0.f,0.f,0.f);
  for (int base = i0; base < i1; base += 512){
    int m = i1 - base; if (m > 512) m = 512;
    __syncthreads();
    for (int idx = t; idx < m; idx += 256) sord[idx] = order[base + idx];
    __syncthreads();
    for (int j = sub; j < m; j += 8){
      long long oe = sord[j];
      float4 v = *(const float4*)&ea[oe*128 + lane*4];
      acc.x += v.x; acc.y += v.y; acc.z += v.z; acc.w += v.w;
    }
  }
  // reduce 8 subgroups -> facc[128], then one global flush
  if (t < 128) facc[t] = 0.f;
  __syncthreads();
  float* a = &facc[lane*4];
  atomicAdd(a+0, acc.x); atomicAdd(a+1, acc.y);
  atomicAdd(a+2, acc.z); atomicAdd(a+3, acc.w);
  __syncthreads();
  if (t < 128 && facc[t] != 0.f) atomicAdd(&pooled_e[g*128 + t], facc[t]);
}

// ---------------- final: combine + edge_w GEMM + MLP, one block per graph
__global__ __launch_bounds__(128) void k_final(
  const float* __restrict__ pooled_gat, const float* __restrict__ pooled_e,
  const float* __restrict__ cnt_n, const float* __restrict__ cnt_e,
  const float* __restrict__ gat_bias, const float* __restrict__ edge_w,
  const float* __restrict__ edge_b, const float* __restrict__ w1,
  const float* __restrict__ b1, const float* __restrict__ w2,
  const float* __restrict__ b2, float* __restrict__ out)
{
  __shared__ float lds_e[128], comb[128], t1[32];
  int g = blockIdx.x, c = threadIdx.x;
  lds_e[c] = pooled_e[g*128 + c];
  __syncthreads();
  float acc = pooled_gat[g*128 + c] + cnt_n[g]*gat_bias[c] + cnt_e[g]*edge_b[c];
  for (int k=0; k<128; ++k) acc += lds_e[k] * edge_w[k*128 + c];
  comb[c] = acc;
  __syncthreads();
  if (c < 32){
    float tv = b1[c];
    for (int k=0; k<128; ++k) tv += comb[k] * w1[k*32 + c];
    t1[c] = tv;
  }
  __syncthreads();
  if (c == 0){
    float o = b2[0];
    #pragma unroll
    for (int m=0; m<32; ++m) o += t1[m] * w2[m];
    out[g] = o;
  }
}

extern "C" void kernel_launch(void* const* d_in, const int* in_sizes, int n_in,
                              void* d_out, int out_size, void* d_ws, size_t ws_size,
                              hipStream_t stream) {
  const float* x        = (const float*)d_in[0];
  const int*   ei       = (const int*)d_in[1];
  const float* ea       = (const float*)d_in[2];
  const int*   batch    = (const int*)d_in[3];
  const float* lin_w    = (const float*)d_in[4];
  const float* att_src  = (const float*)d_in[5];
  const float* att_dst  = (const float*)d_in[6];
  const float* gat_bias = (const float*)d_in[7];
  const float* edge_w   = (const float*)d_in[8];
  const float* edge_b   = (const float*)d_in[9];
  const float* w1       = (const float*)d_in[10];
  const float* b1       = (const float*)d_in[11];
  const float* w2       = (const float*)d_in[12];
  const float* b2       = (const float*)d_in[13];
  float* out = (float*)d_out;

  int N = in_sizes[0] / 128;
  int E = in_sizes[1] / 2;
  const int* src = ei;
  const int* dst = ei + E;

  char* ws = (char*)d_ws;
  size_t off = 0;
  // ---- zeroed region ----
  float* P          = (float*)(ws + off); off += (size_t)NG*2*N*4;
  float* pooled_gat = (float*)(ws + off); off += (size_t)NG*128*4;
  float* pooled_e   = (float*)(ws + off); off += (size_t)NG*128*4;
  float* cnt_n      = (float*)(ws + off); off += NG*4;
  float* cnt_e      = (float*)(ws + off); off += NG*4;
  int*   gcnt       = (int*)  (ws + off); off += NG*4;
  size_t zero_bytes = off;
  // ---- non-zeroed scratch ----
  float* h       = (float*)(ws + off); off += (size_t)N*128*4;
  float* aS      = (float*)(ws + off); off += (size_t)2*N*4;
  float* aD      = (float*)(ws + off); off += (size_t)2*N*4;
  unsigned* emax = (unsigned*)(ws + off); off += (size_t)2*N*4;
  float* denom   = (float*)(ws + off); off += (size_t)2*N*4;
  int*   g_e     = (int*)  (ws + off); off += (size_t)E*4;
  int*   order   = (int*)  (ws + off); off += (size_t)E*4;
  int*   goff    = (int*)  (ws + off); off += NG*4;
  int*   gpos    = (int*)  (ws + off); off += NG*4;

  hipMemsetAsync(d_ws, 0, zero_bytes, stream);

  // edge_attr branch (independent chain)
  k_edge_graph<<<(E+255)/256, 256, 0, stream>>>(src, batch, g_e, gcnt, E);
  k_scan      <<<1, 64, 0, stream>>>(gcnt, goff, gpos, cnt_e);
  k_scatter   <<<(E+255)/256, 256, 0, stream>>>(g_e, order, gpos, E);
  k_eattr_sum <<<NG*EA_SPLITS, 256, 0, stream>>>(ea, order, goff, gcnt, pooled_e);

  // GAT branch
  k_gemm_h    <<<(N+31)/32, 256, 0, stream>>>(x, lin_w, h, N);
  k_node_attn <<<N, 128, 0, stream>>>(h, att_src, att_dst, aS, aD, emax, N);
  k_edge_max  <<<(E+255)/256, 256, 0, stream>>>(src, dst, aS, aD, emax, E);
  k_node_denom<<<(N+255)/256, 256, 0, stream>>>(aS, aD, emax, denom, batch, cnt_n, N);
  k_edge_denom<<<(E+255)/256, 256, 0, stream>>>(src, dst, aS, aD, emax, denom, E);
  k_node_self <<<(N+255)/256, 256, 0, stream>>>(aS, aD, emax, denom, batch, P, N);
  k_edge_alpha<<<(E+255)/256, 256, 0, stream>>>(src, dst, aS, aD, emax, denom, batch, P, N, E);
  k_pgemm     <<<(N+255)/256, 128, 0, stream>>>(P, h, pooled_gat, N);

  k_final     <<<NG, 128, 0, stream>>>(pooled_gat, pooled_e, cnt_n, cnt_e,
                                       gat_bias, edge_w, edge_b, w1, b1, w2, b2, out);
}